// Round 1
// baseline (14785.155 us; speedup 1.0000x reference)
//
#include <hip/hip_runtime.h>

// ---------------- constants ----------------
// B=64, S=256, T=64, E=256, H=256, G=4H=1024, VT=32000

typedef unsigned short u16;
typedef short s8v __attribute__((ext_vector_type(8)));
typedef float f32x4 __attribute__((ext_vector_type(4)));
typedef unsigned short us4 __attribute__((ext_vector_type(4)));

#define MFMA16(a,b,c) __builtin_amdgcn_mfma_f32_16x16x32_bf16(a,b,c,0,0,0)

__device__ __forceinline__ float b2f(u16 u){ union{unsigned int i; float f;} v; v.i = ((unsigned)u)<<16; return v.f; }
__device__ __forceinline__ u16 f2b(float f){ union{float f; unsigned int i;} v; v.f=f; unsigned r = v.i + 0x7FFFu + ((v.i>>16)&1u); return (u16)(r>>16); }
__device__ __forceinline__ float sigf(float x){ return 1.f/(1.f+__expf(-x)); }
__device__ __forceinline__ float tanh_(float x){ x = fminf(15.f,fmaxf(-15.f,x)); float e=__expf(2.f*x); return (e-1.f)/(e+1.f); }

union FU { s8v v; us4 h[2]; };

// Fragment loaders. Same k-bijection for A and B => hardware k-layout cancels.
__device__ __forceinline__ s8v gfrag(const u16* rowp, int kbase, int g4){
  FU u; const u16* p = rowp + kbase + 4*g4;
  u.h[0] = *(const us4*)p; u.h[1] = *(const us4*)(p+16);
  return u.v;
}
// LDS variant with 8B-granule XOR swizzle (granule ^= row&7) to kill the
// 16-way same-bank pattern on stride-512B row reads.
__device__ __forceinline__ s8v ldsfrag(const u16* lds, int ldk, int row, int kbase, int g4){
  int sw = row&7;
  int g0 = ((kbase+4*g4)>>2)^sw, g1 = ((kbase+16+4*g4)>>2)^sw;
  FU u;
  u.h[0] = *(const us4*)&lds[row*ldk + (g0<<2)];
  u.h[1] = *(const us4*)&lds[row*ldk + (g1<<2)];
  return u.v;
}

// ---------------- prep: f32 -> bf16 weight conversions / relayouts ----------------
__global__ __launch_bounds__(256) void prep_kernel(
    const float* Wihf, const float* Whhf, const float* Wihb, const float* Whhb,
    const float* d0Wih, const float* d0Whh, const float* d1Wih, const float* d1Whh,
    const float* attnW, const float* projW,
    u16* oWihf, u16* oWhhf, u16* oWihb, u16* oWhhb,
    u16* oW0, u16* oW1, u16* oWaH, u16* oWaE, u16* oprojW){
  long long i = (long long)blockIdx.x*256 + threadIdx.x;
  const long long N1 = 262144;
  if (i < N1){ oWihf[i] = f2b(Wihf[i]); return; } i -= N1;
  if (i < N1){ oWhhf[i] = f2b(Whhf[i]); return; } i -= N1;
  if (i < N1){ oWihb[i] = f2b(Wihb[i]); return; } i -= N1;
  if (i < N1){ oWhhb[i] = f2b(Whhb[i]); return; } i -= N1;
  if (i < 1048576){ // W0cat [1024][1024] = [Wih0(768) | Whh0(256)]
    int g = (int)(i>>10), k = (int)(i&1023);
    float v = (k<768) ? d0Wih[(size_t)g*768+k] : d0Whh[(size_t)g*256 + (k-768)];
    oW0[i] = f2b(v); return;
  } i -= 1048576;
  if (i < 524288){ // W1cat [1024][512] = [Wih1(256) | Whh1(256)]
    int g = (int)(i>>9), k = (int)(i&511);
    float v = (k<256) ? d1Wih[(size_t)g*256+k] : d1Whh[(size_t)g*256 + (k-256)];
    oW1[i] = f2b(v); return;
  } i -= 524288;
  if (i < 65536){ // WaH [256][256] = attn_W[:, 0:256]
    int n = (int)(i>>8), k = (int)(i&255);
    oWaH[i] = f2b(attnW[(size_t)n*768 + k]); return;
  } i -= 65536;
  if (i < 131072){ // WaE [256][512] = attn_W[:, 256:768]
    int n = (int)(i>>9), k = (int)(i&511);
    oWaE[i] = f2b(attnW[(size_t)n*768 + 256 + k]); return;
  } i -= 131072;
  if (i < 8192000){ oprojW[i] = f2b(projW[i]); return; }
}

// ---------------- gather: embeddings -> bf16 ----------------
__global__ __launch_bounds__(256) void gather_kernel(
    const int* src, const int* tgt, const float* src_emb, const float* tgt_emb,
    u16* xs, u16* temb){
  long long i = (long long)blockIdx.x*256 + threadIdx.x;
  if (i < 4194304){ // xs[s*64+b][e] = src_emb[src[b][s]][e]
    int e = (int)(i&255); int sb = (int)(i>>8);
    int s = sb>>6, b = sb&63;
    int idx = src[b*256 + s];
    xs[i] = f2b(src_emb[(size_t)idx*256 + e]);
    return;
  }
  long long j = i - 4194304;
  if (j < 1048576){ // temb[t*64+b][e] = tgt_emb[tgt[b][t]][e]
    int e = (int)(j&255); int tb = (int)(j>>8);
    int t = tb>>6, b = tb&63;
    int idx = tgt[b*64 + t];
    temb[j] = f2b(tgt_emb[(size_t)idx*256 + e]);
  }
}

// ---------------- generic 64x64-tile MFMA GEMM: C = A @ B^T + bias ----------------
// A: [M][K] bf16, Bw: [N][K] bf16, C: [M][ldc] (bf16 or f32)
template<int K, int OBF>
__global__ __launch_bounds__(256) void gemm64(
    const u16* __restrict__ A, int lda, const u16* __restrict__ Bw, int ldb,
    const float* __restrict__ bias, void* Cout, long long ldc){
  __shared__ u16 Alds[64*K];
  int tid = threadIdx.x;
  long long mt = blockIdx.x, nt = blockIdx.y;
  const int Kc8 = K>>3;
  for (int it = tid; it < 64*Kc8; it += 256){
    int row = it / Kc8, seg = it % Kc8;
    const u16* src = A + (size_t)(mt*64+row)*lda + seg*8;
    us4 a0 = *(const us4*)src, a1 = *(const us4*)(src+4);
    int sw = row&7;
    *(us4*)&Alds[row*K + ((((seg*2  ))^sw)<<2)] = a0;
    *(us4*)&Alds[row*K + ((((seg*2+1))^sw)<<2)] = a1;
  }
  __syncthreads();
  int w = tid>>6, lane = tid&63;
  int l15 = lane&15, g4 = lane>>4;
  int arow = w*16 + l15;
  const int NKT = K>>5;
  s8v af[NKT];
  #pragma unroll
  for (int kt=0; kt<NKT; ++kt) af[kt] = ldsfrag(Alds, K, arow, kt*32, g4);
  f32x4 acc[4];
  #pragma unroll
  for (int nti=0; nti<4; ++nti){
    const u16* brow = Bw + (size_t)(nt*64 + nti*16 + l15)*ldb;
    f32x4 a = {0.f,0.f,0.f,0.f};
    #pragma unroll
    for (int kt=0; kt<NKT; ++kt) a = MFMA16(af[kt], gfrag(brow, kt*32, g4), a);
    acc[nti] = a;
  }
  #pragma unroll
  for (int nti=0; nti<4; ++nti)
    #pragma unroll
    for (int r=0; r<4; ++r){
      long long rowg = mt*64 + w*16 + 4*g4 + r;
      long long colg = nt*64 + nti*16 + l15;
      float v = acc[nti][r] + bias[colg];
      if (OBF) ((u16*)Cout)[rowg*ldc + colg] = f2b(v);
      else     ((float*)Cout)[rowg*ldc + colg] = v;
    }
}

// ---------------- encoder recurrence (persistent, no grid sync) ----------------
// 8 WGs: (dir, rowblock-of-16). 8 waves/WG, wave owns h-chunk of 32.
__global__ __launch_bounds__(512) void encoder_kernel(
    const u16* __restrict__ XWf, const u16* __restrict__ XWb,
    const u16* __restrict__ Whhf, const u16* __restrict__ Whhb,
    u16* __restrict__ enc_out, float* hTf, float* cTf, float* hTb, float* cTb){
  int dir = blockIdx.x & 1, rb = (int)(blockIdx.x>>1)*16;
  const u16* XW  = dir ? XWb : XWf;
  const u16* Whh = dir ? Whhb : Whhf;
  float* hT = dir ? hTb : hTf; float* cT = dir ? cTb : cTf;
  __shared__ u16 hbuf[2][16*256];
  int tid = threadIdx.x, w = tid>>6, lane = tid&63;
  int l15 = lane&15, g4 = lane>>4;
  int hc = w*32;
  for (int i=tid; i<4096; i+=512) hbuf[0][i] = 0;
  __syncthreads();
  float cst[2][4] = {{0.f,0.f,0.f,0.f},{0.f,0.f,0.f,0.f}};
  float hl[2][4];
  for (int t=0; t<256; ++t){
    int s = dir ? (255-t) : t;
    int cur = t&1, nxt = cur^1;
    s8v afr[8];
    #pragma unroll
    for (int kt=0; kt<8; ++kt) afr[kt] = ldsfrag(hbuf[cur], 256, l15, kt*32, g4);
    f32x4 acc[2][4];
    #pragma unroll
    for (int ch=0; ch<2; ++ch)
      #pragma unroll
      for (int q=0; q<4; ++q){
        const u16* brow = Whh + (size_t)(q*256 + hc + ch*16 + l15)*256;
        f32x4 a = {0.f,0.f,0.f,0.f};
        #pragma unroll
        for (int kt=0; kt<8; ++kt) a = MFMA16(afr[kt], gfrag(brow, kt*32, g4), a);
        acc[ch][q] = a;
      }
    #pragma unroll
    for (int ch=0; ch<2; ++ch)
      #pragma unroll
      for (int r=0; r<4; ++r){
        int row = 4*g4 + r; int bg = rb + row;
        int col = hc + ch*16 + l15;
        const u16* xw = XW + (size_t)(s*64 + bg)*1024 + col;
        float gi = acc[ch][0][r] + b2f(xw[0]);
        float gf = acc[ch][1][r] + b2f(xw[256]);
        float gg = acc[ch][2][r] + b2f(xw[512]);
        float go = acc[ch][3][r] + b2f(xw[768]);
        float iv=sigf(gi), fv=sigf(gf), gv=tanh_(gg), ov=sigf(go);
        float cn = fv*cst[ch][r] + iv*gv; cst[ch][r] = cn;
        float hv = ov*tanh_(cn); hl[ch][r] = hv;
        int gcol = (col>>2) ^ (row&7);
        hbuf[nxt][row*256 + (gcol<<2) + (col&3)] = f2b(hv);
        enc_out[((size_t)bg*256 + s)*512 + dir*256 + col] = f2b(hv);
      }
    __syncthreads();
  }
  #pragma unroll
  for (int ch=0; ch<2; ++ch)
    #pragma unroll
    for (int r=0; r<4; ++r){
      int row = 4*g4 + r; int bg = rb + row; int col = hc + ch*16 + l15;
      hT[bg*256+col] = hl[ch][r];
      cT[bg*256+col] = cst[ch][r];
    }
}

// ---------------- decoder init states ----------------
__global__ __launch_bounds__(256) void init_states(
    const float* hTf, const float* hTb, const float* cTf, const float* cTb,
    float* h1g, float* c0g, float* c1g, u16* h0bf){
  int i = blockIdx.x*256 + threadIdx.x; // 16384
  float h = hTf[i] + hTb[i];
  float c = cTf[i] + cTb[i];
  h1g[i] = h; c0g[i] = c; c1g[i] = c; h0bf[i] = f2b(h);
}

// ---------------- grid barrier (monotonic counter, agent scope) ----------------
__device__ __forceinline__ void gridbar(int* cnt, int* tgt){
  __syncthreads();
  if (threadIdx.x == 0){
    *tgt += 256;
    __threadfence();
    __hip_atomic_fetch_add(cnt, 1, __ATOMIC_RELEASE, __HIP_MEMORY_SCOPE_AGENT);
    while (__hip_atomic_load(cnt, __ATOMIC_ACQUIRE, __HIP_MEMORY_SCOPE_AGENT) < *tgt)
      __builtin_amdgcn_s_sleep(2);
    __threadfence();
  }
  __syncthreads();
}

// ---------------- decoder persistent kernel: 256 WGs x 256 thr ----------------
__global__ __launch_bounds__(256) void decoder_kernel(
    const u16* __restrict__ epb, const u16* __restrict__ enc, const u16* __restrict__ temb,
    const u16* __restrict__ WaH, const u16* __restrict__ W0cat, const u16* __restrict__ W1cat,
    const float* __restrict__ attn_v, const float* __restrict__ b0bias, const float* __restrict__ b1bias,
    float* h1g, float* c0g, float* c1g, u16* h0bf,
    u16* x0, u16* x1, float* score, u16* dout, int* barcnt){
  int w = blockIdx.x, tid = threadIdx.x;
  int lane = tid&63, wv = tid>>6;
  int bq = w>>2, r4 = w&3;
  __shared__ float h1s[256], qs[256], vs[256], scs[256], af2[256];
  __shared__ float wred[4];
  __shared__ float ctxp[2][128];
  __shared__ float red[4][4][16][16];
  int bt = 0;
  for (int tt=0; tt<64; ++tt){
    // ======== Phase A: state copies + q = h1@WaH^T + scores ========
    if (r4 == 1) x0[bq*1024 + 768 + tid] = h0bf[bq*256 + tid];
    if (r4 == 2) x1[bq*512  + 256 + tid] = f2b(h1g[bq*256 + tid]);
    h1s[tid] = h1g[bq*256 + tid];
    vs[tid]  = attn_v[tid];
    __syncthreads();
    {
      const u16* wr = WaH + (size_t)tid*256;
      float qv = 0.f;
      for (int k=0; k<256; k+=4){
        us4 w4 = *(const us4*)(wr + k);
        qv += h1s[k]*b2f(w4[0]) + h1s[k+1]*b2f(w4[1]) + h1s[k+2]*b2f(w4[2]) + h1s[k+3]*b2f(w4[3]);
      }
      qs[tid] = qv;
    }
    __syncthreads();
    for (int ii=0; ii<16; ++ii){
      int s = r4*64 + wv*16 + ii;
      const u16* epp = epb + ((size_t)(bq*256 + s))*256 + lane*4;
      us4 e4 = *(const us4*)epp;
      float p = 0.f;
      #pragma unroll
      for (int j=0; j<4; ++j){
        float e = tanh_(b2f(e4[j]) + qs[lane*4+j]);
        p += e * vs[lane*4+j];
      }
      #pragma unroll
      for (int off=32; off; off>>=1) p += __shfl_xor(p, off);
      if (lane == 0) score[bq*256 + s] = p;
    }
    gridbar(barcnt, &bt);
    // ======== Phase B: softmax + ctx + assemble x0 ========
    scs[tid] = score[bq*256 + tid];
    __syncthreads();
    float v = scs[tid];
    #pragma unroll
    for (int off=32; off; off>>=1) v = fmaxf(v, __shfl_xor(v, off));
    if (lane == 0) wred[wv] = v;
    __syncthreads();
    float mx = fmaxf(fmaxf(wred[0],wred[1]), fmaxf(wred[2],wred[3]));
    float e = __expf(scs[tid] - mx);
    af2[tid] = e;
    float ssum = e;
    #pragma unroll
    for (int off=32; off; off>>=1) ssum += __shfl_xor(ssum, off);
    __syncthreads();
    if (lane == 0) wred[wv] = ssum;
    __syncthreads();
    float den = wred[0]+wred[1]+wred[2]+wred[3];
    {
      int d = r4*128 + (tid&127), sh = tid>>7;
      const u16* ebase = enc + ((size_t)bq*256)*512 + d;
      float cx = 0.f;
      for (int s2=0; s2<128; ++s2){
        int s = sh*128 + s2;
        cx += af2[s] * b2f(ebase[(size_t)s*512]);
      }
      ctxp[sh][tid&127] = cx;
    }
    __syncthreads();
    if (tid < 128){
      float cxv = (ctxp[0][tid] + ctxp[1][tid]) / den;
      x0[bq*1024 + 256 + r4*128 + tid] = f2b(cxv);
    }
    if (r4 == 0) x0[bq*1024 + tid] = temb[((size_t)tt*64 + bq)*256 + tid];
    gridbar(barcnt, &bt);
    // ======== Phase C: dec0 cell, g = x0 @ W0cat^T + b0 ========
    if (w < 64){
      int mt = w>>4, hcc = (w&15)*16;
      int l15 = lane&15, g4l = lane>>4;
      const u16* arow = x0 + (size_t)(mt*16 + l15)*1024 + wv*256;
      s8v afr[8];
      #pragma unroll
      for (int kt=0; kt<8; ++kt) afr[kt] = gfrag(arow, kt*32, g4l);
      #pragma unroll
      for (int q=0; q<4; ++q){
        const u16* brow = W0cat + (size_t)(q*256 + hcc + l15)*1024 + wv*256;
        f32x4 a = {0.f,0.f,0.f,0.f};
        #pragma unroll
        for (int kt=0; kt<8; ++kt) a = MFMA16(afr[kt], gfrag(brow, kt*32, g4l), a);
        #pragma unroll
        for (int r=0; r<4; ++r) red[wv][q][4*g4l+r][l15] = a[r];
      }
    }
    __syncthreads();
    if (w < 64){
      int mt = w>>4, hcc = (w&15)*16;
      int row = tid>>4, colx = tid&15;
      int bg = mt*16 + row, hcol = hcc + colx;
      float g[4];
      #pragma unroll
      for (int q=0; q<4; ++q)
        g[q] = red[0][q][row][colx]+red[1][q][row][colx]+red[2][q][row][colx]+red[3][q][row][colx]
             + b0bias[q*256 + hcol];
      float iv=sigf(g[0]), fv=sigf(g[1]), gv=tanh_(g[2]), ov=sigf(g[3]);
      float cn = fv*c0g[bg*256+hcol] + iv*gv; c0g[bg*256+hcol] = cn;
      float hv = ov*tanh_(cn);
      u16 hb = f2b(hv);
      h0bf[bg*256+hcol] = hb;
      x1[bg*512 + hcol] = hb;
    }
    gridbar(barcnt, &bt);
    // ======== Phase D: dec1 cell, g = x1 @ W1cat^T + b1 ========
    if (w < 64){
      int mt = w>>4, hcc = (w&15)*16;
      int l15 = lane&15, g4l = lane>>4;
      const u16* arow = x1 + (size_t)(mt*16 + l15)*512 + wv*128;
      s8v afr[4];
      #pragma unroll
      for (int kt=0; kt<4; ++kt) afr[kt] = gfrag(arow, kt*32, g4l);
      #pragma unroll
      for (int q=0; q<4; ++q){
        const u16* brow = W1cat + (size_t)(q*256 + hcc + l15)*512 + wv*128;
        f32x4 a = {0.f,0.f,0.f,0.f};
        #pragma unroll
        for (int kt=0; kt<4; ++kt) a = MFMA16(afr[kt], gfrag(brow, kt*32, g4l), a);
        #pragma unroll
        for (int r=0; r<4; ++r) red[wv][q][4*g4l+r][l15] = a[r];
      }
    }
    __syncthreads();
    if (w < 64){
      int mt = w>>4, hcc = (w&15)*16;
      int row = tid>>4, colx = tid&15;
      int bg = mt*16 + row, hcol = hcc + colx;
      float g[4];
      #pragma unroll
      for (int q=0; q<4; ++q)
        g[q] = red[0][q][row][colx]+red[1][q][row][colx]+red[2][q][row][colx]+red[3][q][row][colx]
             + b1bias[q*256 + hcol];
      float iv=sigf(g[0]), fv=sigf(g[1]), gv=tanh_(g[2]), ov=sigf(g[3]);
      float cn = fv*c1g[bg*256+hcol] + iv*gv; c1g[bg*256+hcol] = cn;
      float hv = ov*tanh_(cn);
      h1g[bg*256+hcol] = hv;
      dout[((size_t)bg*64 + tt)*256 + hcol] = f2b(hv);
    }
    gridbar(barcnt, &bt);
  }
}

// ---------------- host launcher ----------------
extern "C" void kernel_launch(void* const* d_in, const int* in_sizes, int n_in,
                              void* d_out, int out_size, void* d_ws, size_t ws_size,
                              hipStream_t stream){
  const int*   src     = (const int*)  d_in[0];
  const int*   tgt     = (const int*)  d_in[1];
  const float* src_emb = (const float*)d_in[2];
  const float* tgt_emb = (const float*)d_in[3];
  const float* encfWih = (const float*)d_in[4];
  const float* encfWhh = (const float*)d_in[5];
  const float* encfb   = (const float*)d_in[6];
  const float* encbWih = (const float*)d_in[7];
  const float* encbWhh = (const float*)d_in[8];
  const float* encbb   = (const float*)d_in[9];
  const float* d0Wih   = (const float*)d_in[10];
  const float* d0Whh   = (const float*)d_in[11];
  const float* d0b     = (const float*)d_in[12];
  const float* d1Wih   = (const float*)d_in[13];
  const float* d1Whh   = (const float*)d_in[14];
  const float* d1b     = (const float*)d_in[15];
  const float* attnW   = (const float*)d_in[16];
  const float* attnb   = (const float*)d_in[17];
  const float* attnv   = (const float*)d_in[18];
  const float* projW   = (const float*)d_in[19];
  const float* projb   = (const float*)d_in[20];

  char* ws = (char*)d_ws;
  size_t off = 0;
  auto alloc = [&](size_t bytes)->char*{ char* p = ws + off; off += (bytes + 255) & ~(size_t)255; return p; };

  int* barcnt   = (int*)alloc(256);
  u16* xs       = (u16*)alloc(16384ULL*256*2);
  u16* temb     = (u16*)alloc(4096ULL*256*2);
  u16* oWihf    = (u16*)alloc(262144ULL*2);
  u16* oWhhf    = (u16*)alloc(262144ULL*2);
  u16* oWihb    = (u16*)alloc(262144ULL*2);
  u16* oWhhb    = (u16*)alloc(262144ULL*2);
  u16* oW0      = (u16*)alloc(1048576ULL*2);
  u16* oW1      = (u16*)alloc(524288ULL*2);
  u16* oWaH     = (u16*)alloc(65536ULL*2);
  u16* oWaE     = (u16*)alloc(131072ULL*2);
  u16* oprojW   = (u16*)alloc(8192000ULL*2);
  u16* XWf      = (u16*)alloc(16384ULL*1024*2);
  u16* XWb      = (u16*)alloc(16384ULL*1024*2);
  u16* enc      = (u16*)alloc(64ULL*256*512*2);
  u16* epb      = (u16*)alloc(64ULL*256*256*2);
  float* hTf    = (float*)alloc(16384ULL*4);
  float* cTf    = (float*)alloc(16384ULL*4);
  float* hTb    = (float*)alloc(16384ULL*4);
  float* cTb    = (float*)alloc(16384ULL*4);
  float* h1g    = (float*)alloc(16384ULL*4);
  float* c0g    = (float*)alloc(16384ULL*4);
  float* c1g    = (float*)alloc(16384ULL*4);
  u16* h0bf     = (u16*)alloc(16384ULL*2);
  u16* x0       = (u16*)alloc(64ULL*1024*2);
  u16* x1       = (u16*)alloc(64ULL*512*2);
  float* score  = (float*)alloc(16384ULL*4);
  u16* dout     = (u16*)alloc(4096ULL*256*2);
  if (off > ws_size) return; // ~128 MB needed

  hipMemsetAsync(barcnt, 0, 256, stream);

  prep_kernel<<<43008, 256, 0, stream>>>(encfWih, encfWhh, encbWih, encbWhh,
      d0Wih, d0Whh, d1Wih, d1Whh, attnW, projW,
      oWihf, oWhhf, oWihb, oWhhb, oW0, oW1, oWaH, oWaE, oprojW);

  gather_kernel<<<20480, 256, 0, stream>>>(src, tgt, src_emb, tgt_emb, xs, temb);

  gemm64<256,1><<<dim3(256,16), 256, 0, stream>>>(xs, 256, oWihf, 256, encfb, XWf, 1024);
  gemm64<256,1><<<dim3(256,16), 256, 0, stream>>>(xs, 256, oWihb, 256, encbb, XWb, 1024);

  encoder_kernel<<<8, 512, 0, stream>>>(XWf, XWb, oWhhf, oWhhb, enc, hTf, cTf, hTb, cTb);

  gemm64<512,1><<<dim3(256,4), 256, 0, stream>>>(enc, 512, oWaE, 512, attnb, epb, 256);

  init_states<<<64, 256, 0, stream>>>(hTf, hTb, cTf, cTb, h1g, c0g, c1g, h0bf);

  decoder_kernel<<<256, 256, 0, stream>>>(epb, enc, temb, oWaH, oW0, oW1,
      attnv, d0b, d1b, h1g, c0g, c1g, h0bf, x0, x1, score, dout, barcnt);

  gemm64<256,0><<<dim3(64,500), 256, 0, stream>>>(dout, 256, oprojW, 256, projb, (float*)d_out, 32000);
}

// Round 2
// 5972.603 us; speedup vs baseline: 2.4755x; 2.4755x over previous
//
#include <hip/hip_runtime.h>

// B=64, S=256, T=64, E=256, H=256, G=4H=1024, VT=32000
typedef unsigned short u16;
typedef unsigned int u32;
typedef unsigned long long u64;
typedef short s8v __attribute__((ext_vector_type(8)));
typedef float f32x4 __attribute__((ext_vector_type(4)));
typedef unsigned short us4 __attribute__((ext_vector_type(4)));

#define MFMA16(a,b,c) __builtin_amdgcn_mfma_f32_16x16x32_bf16(a,b,c,0,0,0)

__device__ __forceinline__ float b2f(u16 u){ union{u32 i; float f;} v; v.i=((u32)u)<<16; return v.f; }
__device__ __forceinline__ u16 f2b(float f){ union{float f; u32 i;} v; v.f=f; u32 r=v.i+0x7FFFu+((v.i>>16)&1u); return (u16)(r>>16); }
__device__ __forceinline__ float sigf(float x){ return 1.f/(1.f+__expf(-x)); }
__device__ __forceinline__ float tanh_(float x){ x=fminf(15.f,fmaxf(-15.f,x)); float e=__expf(2.f*x); return (e-1.f)/(e+1.f); }

union FU { s8v v; us4 h[2]; };

// sc1 (bypass-L2, cross-XCD coherent) access helpers: relaxed agent-scope atomics.
__device__ __forceinline__ us4 ld8_sys(const u16* p){
  u64 v = __hip_atomic_load((const u64*)p, __ATOMIC_RELAXED, __HIP_MEMORY_SCOPE_AGENT);
  union{u64 q; us4 h;} x; x.q=v; return x.h;
}
__device__ __forceinline__ u32 ld4_sys(const u16* p){
  return __hip_atomic_load((const u32*)p, __ATOMIC_RELAXED, __HIP_MEMORY_SCOPE_AGENT);
}
__device__ __forceinline__ void st4_sys(u16* p, u32 v){
  __hip_atomic_store((u32*)p, v, __ATOMIC_RELAXED, __HIP_MEMORY_SCOPE_AGENT);
}
__device__ __forceinline__ int ldcnt(const int* p){
  return __hip_atomic_load(p, __ATOMIC_RELAXED, __HIP_MEMORY_SCOPE_AGENT);
}
__device__ __forceinline__ void addcnt(int* p){
  __hip_atomic_fetch_add(p, 1, __ATOMIC_RELAXED, __HIP_MEMORY_SCOPE_AGENT);
}

// Fragment loaders; A and B use the same k-bijection so the HW k-layout cancels.
__device__ __forceinline__ s8v gfrag(const u16* rowp, int kbase, int g4){
  FU u; const u16* p = rowp + kbase + 4*g4;
  u.h[0] = *(const us4*)p; u.h[1] = *(const us4*)(p+16);
  return u.v;
}
__device__ __forceinline__ s8v sgfrag(const u16* rowp, int kbase, int g4){
  FU u; const u16* p = rowp + kbase + 4*g4;
  u.h[0] = ld8_sys(p); u.h[1] = ld8_sys(p+16);
  return u.v;
}
// LDS frag with 8B-granule XOR swizzle (granule ^= row&7).
__device__ __forceinline__ s8v ldsfrag(const u16* lds, int ldk, int row, int kbase, int g4){
  int sw = row&7;
  int g0 = ((kbase+4*g4)>>2)^sw, g1 = ((kbase+16+4*g4)>>2)^sw;
  FU u;
  u.h[0] = *(const us4*)&lds[row*ldk + (g0<<2)];
  u.h[1] = *(const us4*)&lds[row*ldk + (g1<<2)];
  return u.v;
}

// ---------------- prep: f32 -> bf16 weight conversions / relayouts ----------------
__global__ __launch_bounds__(256) void prep_kernel(
    const float* Wihf, const float* Whhf, const float* Wihb, const float* Whhb,
    const float* d0Wih, const float* d0Whh, const float* d1Wih, const float* d1Whh,
    const float* attnW, const float* projW,
    u16* oWihf, u16* oWhhf, u16* oWihb, u16* oWhhb,
    u16* oW0, u16* oW1, u16* oWaH, u16* oWaE, u16* oprojW){
  long long i = (long long)blockIdx.x*256 + threadIdx.x;
  const long long N1 = 262144;
  if (i < N1){ oWihf[i] = f2b(Wihf[i]); return; } i -= N1;
  if (i < N1){ oWhhf[i] = f2b(Whhf[i]); return; } i -= N1;
  if (i < N1){ oWihb[i] = f2b(Wihb[i]); return; } i -= N1;
  if (i < N1){ oWhhb[i] = f2b(Whhb[i]); return; } i -= N1;
  if (i < 1048576){ // W0cat [1024][1024] = [Wih0(768) | Whh0(256)]
    int g = (int)(i>>10), k = (int)(i&1023);
    float v = (k<768) ? d0Wih[(size_t)g*768+k] : d0Whh[(size_t)g*256 + (k-768)];
    oW0[i] = f2b(v); return;
  } i -= 1048576;
  if (i < 524288){ // W1cat [1024][512] = [Wih1(256) | Whh1(256)]
    int g = (int)(i>>9), k = (int)(i&511);
    float v = (k<256) ? d1Wih[(size_t)g*256+k] : d1Whh[(size_t)g*256 + (k-256)];
    oW1[i] = f2b(v); return;
  } i -= 524288;
  if (i < 65536){ int n=(int)(i>>8), k=(int)(i&255); oWaH[i] = f2b(attnW[(size_t)n*768+k]); return; } i -= 65536;
  if (i < 131072){ int n=(int)(i>>9), k=(int)(i&511); oWaE[i] = f2b(attnW[(size_t)n*768+256+k]); return; } i -= 131072;
  if (i < 8192000){ oprojW[i] = f2b(projW[i]); return; }
}

// ---------------- gather ----------------
__global__ __launch_bounds__(256) void gather_kernel(
    const int* src, const int* tgt, const float* src_emb, const float* tgt_emb,
    u16* xs, u16* temb){
  long long i = (long long)blockIdx.x*256 + threadIdx.x;
  if (i < 4194304){
    int e = (int)(i&255); int sb = (int)(i>>8);
    int s = sb>>6, b = sb&63;
    int idx = src[b*256 + s];
    xs[i] = f2b(src_emb[(size_t)idx*256 + e]);
    return;
  }
  long long j = i - 4194304;
  if (j < 1048576){
    int e = (int)(j&255); int tb = (int)(j>>8);
    int t = tb>>6, b = tb&63;
    int idx = tgt[b*64 + t];
    temb[j] = f2b(tgt_emb[(size_t)idx*256 + e]);
  }
}

// ---------------- 64x64-tile MFMA GEMM: C = A @ B^T + bias ----------------
template<int K, int OBF>
__global__ __launch_bounds__(256) void gemm64(
    const u16* __restrict__ A, int lda, const u16* __restrict__ Bw, int ldb,
    const float* __restrict__ bias, void* Cout, long long ldc){
  __shared__ u16 Alds[64*K];
  int tid = threadIdx.x;
  long long mt = blockIdx.x, nt = blockIdx.y;
  const int Kc8 = K>>3;
  for (int it = tid; it < 64*Kc8; it += 256){
    int row = it / Kc8, seg = it % Kc8;
    const u16* src = A + (size_t)(mt*64+row)*lda + seg*8;
    us4 a0 = *(const us4*)src, a1 = *(const us4*)(src+4);
    int sw = row&7;
    *(us4*)&Alds[row*K + ((((seg*2  ))^sw)<<2)] = a0;
    *(us4*)&Alds[row*K + ((((seg*2+1))^sw)<<2)] = a1;
  }
  __syncthreads();
  int w = tid>>6, lane = tid&63;
  int l15 = lane&15, g4 = lane>>4;
  int arow = w*16 + l15;
  const int NKT = K>>5;
  s8v af[NKT];
  #pragma unroll
  for (int kt=0; kt<NKT; ++kt) af[kt] = ldsfrag(Alds, K, arow, kt*32, g4);
  f32x4 acc[4];
  #pragma unroll
  for (int nti=0; nti<4; ++nti){
    const u16* brow = Bw + (size_t)(nt*64 + nti*16 + l15)*ldb;
    f32x4 a = {0.f,0.f,0.f,0.f};
    #pragma unroll
    for (int kt=0; kt<NKT; ++kt) a = MFMA16(af[kt], gfrag(brow, kt*32, g4), a);
    acc[nti] = a;
  }
  #pragma unroll
  for (int nti=0; nti<4; ++nti)
    #pragma unroll
    for (int r=0; r<4; ++r){
      long long rowg = mt*64 + w*16 + 4*g4 + r;
      long long colg = nt*64 + nti*16 + l15;
      float v = acc[nti][r] + bias[colg];
      if (OBF) ((u16*)Cout)[rowg*ldc + colg] = f2b(v);
      else     ((float*)Cout)[rowg*ldc + colg] = v;
    }
}

// ---------------- encoder: 16 WGs, register-resident Whh, 4-WG group sync ----------------
// WG: dir = bid&1, bb=(bid>>1)&1 (batch block of 32), cb=bid>>2 (64 h-cols).
// wave w: mt=w&1 (16 bq rows), g16=w>>1 (16 h-cols). Whh frags in VGPRs (128/lane).
__global__ __launch_bounds__(512,2) void encoder_kernel(
    const u16* __restrict__ XWf, const u16* __restrict__ XWb,
    const u16* __restrict__ Whhf, const u16* __restrict__ Whhb,
    u16* __restrict__ enc_out, float* hTf, float* cTf, float* hTb, float* cTb,
    u16* hG, int* ecnt){
  int bid = blockIdx.x;
  int dir = bid&1, bb=(bid>>1)&1, cb=bid>>2;
  int grp = dir*2+bb;
  const u16* XW  = dir ? XWb : XWf;
  const u16* Whh = dir ? Whhb : Whhf;
  float* hT = dir ? hTb : hTf; float* cT = dir ? cTb : cTf;
  int tid=threadIdx.x, w=tid>>6, lane=tid&63, l15=lane&15, g4=lane>>4;
  int mt=w&1, g16=w>>1;
  int hc = cb*64 + g16*16 + l15;
  s8v bwf[4][8];
  #pragma unroll
  for (int q=0;q<4;++q)
    #pragma unroll
    for (int kt=0;kt<8;++kt)
      bwf[q][kt] = gfrag(Whh + (size_t)(q*256 + hc)*256, kt*32, g4);
  __shared__ u16 hbuf[32*256];
  for (int i=tid;i<8192;i+=512) hbuf[i]=0;
  __syncthreads();
  float cst[4]={0.f,0.f,0.f,0.f};
  int* cnt = &ecnt[grp*32];
  u16* hGb = hG + (size_t)grp*2*32*256;
  for (int t=0;t<256;++t){
    int s = dir ? 255-t : t;
    s8v af[8];
    #pragma unroll
    for (int kt=0;kt<8;++kt) af[kt] = ldsfrag(hbuf, 256, mt*16+l15, kt*32, g4);
    f32x4 acc[4];
    #pragma unroll
    for (int q=0;q<4;++q){
      f32x4 a={0.f,0.f,0.f,0.f};
      #pragma unroll
      for (int kt=0;kt<8;++kt) a = MFMA16(af[kt], bwf[q][kt], a);
      acc[q]=a;
    }
    #pragma unroll
    for (int r=0;r<4;++r){
      int bql = mt*16 + 4*g4 + r;
      int bg = bb*32 + bql;
      const u16* xw = XW + (size_t)(s*64+bg)*1024 + hc;
      float gi = acc[0][r] + b2f(xw[0]);
      float gf = acc[1][r] + b2f(xw[256]);
      float gg = acc[2][r] + b2f(xw[512]);
      float go = acc[3][r] + b2f(xw[768]);
      float iv=sigf(gi), fv=sigf(gf), gv=tanh_(gg), ov=sigf(go);
      float cn = fv*cst[r]+iv*gv; cst[r]=cn;
      float hv = ov*tanh_(cn);
      enc_out[((size_t)bg*256+s)*512 + dir*256 + hc] = f2b(hv);
      if (t==255){ hT[bg*256+hc]=hv; cT[bg*256+hc]=cn; }
      else {
        int me = f2b(hv);
        int ot = __shfl_xor(me,1);
        if ((l15&1)==0)
          st4_sys(hGb + ((size_t)((t&1)*32) + bql)*256 + hc, ((u32)me&0xFFFFu)|((u32)ot<<16));
      }
    }
    if (t<255){
      asm volatile("s_waitcnt vmcnt(0)" ::: "memory");
      __syncthreads();
      if (tid==0){
        addcnt(cnt);
        while (ldcnt(cnt) < 4*(t+1)) __builtin_amdgcn_s_sleep(4);
      }
      __syncthreads();
      const u16* hGp = hGb + (size_t)((t&1)*32)*256;
      for (int idx=tid; idx<4096; idx+=512){
        int row = idx>>7, cp = (idx&127)*2;
        u32 v = ld4_sys(hGp + row*256 + cp);
        int gcol = (cp>>2) ^ (row&7);
        *(u32*)((char*)hbuf + row*512 + gcol*8 + (cp&3)*2) = v;
      }
      __syncthreads();
    }
  }
}

// ---------------- init decoder states ----------------
__global__ __launch_bounds__(256) void init_states(
    const float* hTf, const float* hTb, const float* cTf, const float* cTb,
    float* c0g, float* c1g, u16* h0buf, u16* h1buf){
  int i = blockIdx.x*256 + threadIdx.x; // 16384
  float h = hTf[i] + hTb[i];
  float c = cTf[i] + cTb[i];
  c0g[i]=c; c1g[i]=c;
  u16 hb = f2b(h);
  h0buf[16384+i] = hb;  // parity-1 slot
  h1buf[16384+i] = hb;
}

// ---------------- decoder: 64 persistent WGs, 3 relaxed barriers/step ----------------
// WG j: owns batch row j for attention; owns h-cols 4j..4j+3 for both LSTM cells.
// W0/W1 slices register-resident; c0/c1 in registers; cross-phase data via sc1.
__global__ __launch_bounds__(512,2) void decoder_kernel(
    const u16* __restrict__ epb, const u16* __restrict__ enc, const u16* __restrict__ temb,
    const u16* __restrict__ WaH, const u16* __restrict__ W0, const u16* __restrict__ W1,
    const float* __restrict__ attn_v, const float* __restrict__ b0, const float* __restrict__ b1,
    const float* __restrict__ c0init, const float* __restrict__ c1init,
    u16* h0buf, u16* h1buf, u16* ctxbuf, u16* dout, int* dcnt){
  int j = blockIdx.x, tid=threadIdx.x, w=tid>>6, lane=tid&63, l15=lane&15, g4=lane>>4;
  int mt=w>>1, kh=w&1;
  s8v b0f[16]; s8v b1f[8];
  {
    int row = (l15>>2)*256 + 4*j + (l15&3);
    #pragma unroll
    for (int kt=0;kt<16;++kt) b0f[kt] = gfrag(W0 + (size_t)row*1024, kh*512+kt*32, g4);
    #pragma unroll
    for (int kt=0;kt<8;++kt)  b1f[kt] = gfrag(W1 + (size_t)row*512,  kh*256+kt*32, g4);
  }
  int cbq = tid>>2, crem = tid&3, hcol = 4*j+crem;
  float c0r=0.f, c1r=0.f, bias0[4], bias1[4];
  if (tid<256){
    c0r = c0init[cbq*256+hcol]; c1r = c1init[cbq*256+hcol];
    #pragma unroll
    for (int q=0;q<4;++q){ bias0[q]=b0[q*256+hcol]; bias1[q]=b1[q*256+hcol]; }
  }
  __shared__ float2 qv[256];
  __shared__ float qp2[2][256];
  __shared__ float sp2[2][256];
  __shared__ float af2[256];
  __shared__ float wred[8];
  __shared__ float red[8][16][16];
  if (tid<256) qv[tid].y = attn_v[tid];
  int tgt = 0;

#define GRIDBAR() do{ \
    tgt += 64; \
    asm volatile("s_waitcnt vmcnt(0)" ::: "memory"); \
    __syncthreads(); \
    if (tid<64){ \
      if (tid==0) addcnt(&dcnt[(j&7)*32]); \
      int sumv; \
      do{ __builtin_amdgcn_s_sleep(4); \
          int v_ = ldcnt(&dcnt[(lane&7)*32]); \
          v_ += __shfl_xor(v_,1); v_ += __shfl_xor(v_,2); v_ += __shfl_xor(v_,4); \
          sumv = v_; \
      } while (sumv < tgt); \
    } \
    __syncthreads(); \
  }while(0)

  for (int tt=0; tt<64; ++tt){
    int par = tt&1, pp = par^1;
    // ======== Phase A: q = WaH @ h1, scores, softmax, ctx ========
    {
      int h = tid&255, k2 = tid>>8;
      const u16* war = WaH + (size_t)h*256 + k2*128;
      const u16* h1p = h1buf + (size_t)(pp*64 + j)*256 + k2*128;
      float qp=0.f;
      #pragma unroll 4
      for (int c=0;c<32;++c){
        us4 hw = ld8_sys(h1p + c*4);
        us4 ww = *(const us4*)(war + c*4);
        qp += b2f(hw[0])*b2f(ww[0]) + b2f(hw[1])*b2f(ww[1])
            + b2f(hw[2])*b2f(ww[2]) + b2f(hw[3])*b2f(ww[3]);
      }
      qp2[k2][h] = qp;
    }
    __syncthreads();
    if (tid<256) qv[tid].x = qp2[0][tid] + qp2[1][tid];
    __syncthreads();
    {
      int s2 = tid&255, h2 = tid>>8;
      const u16* epp = epb + ((size_t)(j*256+s2))*256 + h2*128;
      float p=0.f;
      for (int c=0;c<32;++c){
        us4 e4 = *(const us4*)(epp + c*4);
        #pragma unroll
        for (int jj=0;jj<4;++jj){
          float2 qvv = qv[h2*128 + c*4 + jj];
          p += tanh_(b2f(e4[jj]) + qvv.x) * qvv.y;
        }
      }
      sp2[h2][s2] = p;
    }
    __syncthreads();
    float pv = (tid<256) ? sp2[0][tid]+sp2[1][tid] : -1e30f;
    float m = pv;
    #pragma unroll
    for (int o2=32;o2;o2>>=1) m = fmaxf(m, __shfl_xor(m,o2));
    if (lane==0 && w<4) wred[w]=m;
    __syncthreads();
    float mx = fmaxf(fmaxf(wred[0],wred[1]),fmaxf(wred[2],wred[3]));
    float ev = (tid<256) ? __expf(pv-mx) : 0.f;
    float sm = ev;
    #pragma unroll
    for (int o2=32;o2;o2>>=1) sm += __shfl_xor(sm,o2);
    __syncthreads();            // all reads of wred[0..3] done
    if (lane==0 && w<4) wred[4+w]=sm;
    __syncthreads();
    float den = wred[4]+wred[5]+wred[6]+wred[7];
    if (tid<256) af2[tid] = ev/den;
    __syncthreads();
    {
      int d = tid;
      const u16* ep2 = enc + ((size_t)j*256)*512 + d;
      float cx=0.f;
      #pragma unroll 4
      for (int s3=0;s3<256;++s3) cx += af2[s3]*b2f(ep2[(size_t)s3*512]);
      int me = f2b(cx);
      int ot = __shfl_xor(me,1);
      if ((lane&1)==0) st4_sys(ctxbuf + (size_t)j*512 + d, ((u32)me&0xFFFFu)|((u32)ot<<16));
    }
    GRIDBAR();
    // ======== Phase C: dec0 cell ========
    {
      f32x4 a={0.f,0.f,0.f,0.f};
      int bq = mt*16 + l15;
      const u16* tp  = temb   + ((size_t)tt*64 + bq)*256;
      const u16* cp2 = ctxbuf + (size_t)bq*512;
      const u16* hp  = h0buf  + (size_t)(pp*64 + bq)*256;
      #pragma unroll
      for (int kt=0;kt<16;++kt){
        int gk = kh*16 + kt;
        s8v afr;
        if (gk<8)       afr = gfrag(tp, gk*32, g4);
        else if (gk<24) afr = sgfrag(cp2, (gk-8)*32, g4);
        else            afr = sgfrag(hp, (gk-24)*32, g4);
        a = MFMA16(afr, b0f[kt], a);
      }
      #pragma unroll
      for (int r=0;r<4;++r) red[w][4*g4+r][l15] = a[r];
    }
    __syncthreads();
    if (tid<256){
      int mrow = cbq&15, msel = (cbq>>4)*2;
      float gi = red[msel][mrow][0+crem]+red[msel+1][mrow][0+crem]+bias0[0];
      float gf = red[msel][mrow][4+crem]+red[msel+1][mrow][4+crem]+bias0[1];
      float gg = red[msel][mrow][8+crem]+red[msel+1][mrow][8+crem]+bias0[2];
      float go = red[msel][mrow][12+crem]+red[msel+1][mrow][12+crem]+bias0[3];
      float iv=sigf(gi), fv=sigf(gf), gv=tanh_(gg), ov=sigf(go);
      float cn = fv*c0r+iv*gv; c0r=cn;
      float hv = ov*tanh_(cn);
      int me=f2b(hv), ot=__shfl_xor(me,1);
      if ((tid&1)==0) st4_sys(h0buf + (size_t)(par*64+cbq)*256 + hcol, ((u32)me&0xFFFFu)|((u32)ot<<16));
    }
    GRIDBAR();
    // ======== Phase D: dec1 cell ========
    {
      f32x4 a={0.f,0.f,0.f,0.f};
      int bq = mt*16 + l15;
      const u16* h0p = h0buf + (size_t)(par*64 + bq)*256;
      const u16* h1p = h1buf + (size_t)(pp*64 + bq)*256;
      #pragma unroll
      for (int kt=0;kt<8;++kt){
        int gk = kh*8 + kt;
        s8v afr = (gk<8) ? sgfrag(h0p, gk*32, g4) : sgfrag(h1p, (gk-8)*32, g4);
        a = MFMA16(afr, b1f[kt], a);
      }
      #pragma unroll
      for (int r=0;r<4;++r) red[w][4*g4+r][l15] = a[r];
    }
    __syncthreads();
    if (tid<256){
      int mrow = cbq&15, msel = (cbq>>4)*2;
      float gi = red[msel][mrow][0+crem]+red[msel+1][mrow][0+crem]+bias1[0];
      float gf = red[msel][mrow][4+crem]+red[msel+1][mrow][4+crem]+bias1[1];
      float gg = red[msel][mrow][8+crem]+red[msel+1][mrow][8+crem]+bias1[2];
      float go = red[msel][mrow][12+crem]+red[msel+1][mrow][12+crem]+bias1[3];
      float iv=sigf(gi), fv=sigf(gf), gv=tanh_(gg), ov=sigf(go);
      float cn = fv*c1r+iv*gv; c1r=cn;
      float hv = ov*tanh_(cn);
      int me=f2b(hv), ot=__shfl_xor(me,1);
      if ((tid&1)==0) st4_sys(h1buf + (size_t)(par*64+cbq)*256 + hcol, ((u32)me&0xFFFFu)|((u32)ot<<16));
      dout[((size_t)cbq*64+tt)*256 + hcol] = f2b(hv);
    }
    GRIDBAR();
  }
#undef GRIDBAR
}

// ---------------- host launcher ----------------
extern "C" void kernel_launch(void* const* d_in, const int* in_sizes, int n_in,
                              void* d_out, int out_size, void* d_ws, size_t ws_size,
                              hipStream_t stream){
  const int*   src     = (const int*)  d_in[0];
  const int*   tgt     = (const int*)  d_in[1];
  const float* src_emb = (const float*)d_in[2];
  const float* tgt_emb = (const float*)d_in[3];
  const float* encfWih = (const float*)d_in[4];
  const float* encfWhh = (const float*)d_in[5];
  const float* encfb   = (const float*)d_in[6];
  const float* encbWih = (const float*)d_in[7];
  const float* encbWhh = (const float*)d_in[8];
  const float* encbb   = (const float*)d_in[9];
  const float* d0Wih   = (const float*)d_in[10];
  const float* d0Whh   = (const float*)d_in[11];
  const float* d0b     = (const float*)d_in[12];
  const float* d1Wih   = (const float*)d_in[13];
  const float* d1Whh   = (const float*)d_in[14];
  const float* d1b     = (const float*)d_in[15];
  const float* attnW   = (const float*)d_in[16];
  const float* attnb   = (const float*)d_in[17];
  const float* attnv   = (const float*)d_in[18];
  const float* projW   = (const float*)d_in[19];
  const float* projb   = (const float*)d_in[20];

  char* ws = (char*)d_ws;
  size_t off = 0;
  auto alloc = [&](size_t bytes)->char*{ char* p = ws + off; off += (bytes + 255) & ~(size_t)255; return p; };

  int* dcnt     = (int*)alloc(1024);
  int* ecnt     = (int*)alloc(1024);
  u16* xs       = (u16*)alloc(16384ULL*256*2);
  u16* temb     = (u16*)alloc(4096ULL*256*2);
  u16* oWihf    = (u16*)alloc(262144ULL*2);
  u16* oWhhf    = (u16*)alloc(262144ULL*2);
  u16* oWihb    = (u16*)alloc(262144ULL*2);
  u16* oWhhb    = (u16*)alloc(262144ULL*2);
  u16* oW0      = (u16*)alloc(1048576ULL*2);
  u16* oW1      = (u16*)alloc(524288ULL*2);
  u16* oWaH     = (u16*)alloc(65536ULL*2);
  u16* oWaE     = (u16*)alloc(131072ULL*2);
  u16* oprojW   = (u16*)alloc(8192000ULL*2);
  u16* XWf      = (u16*)alloc(16384ULL*1024*2);
  u16* XWb      = (u16*)alloc(16384ULL*1024*2);
  u16* enc      = (u16*)alloc(64ULL*256*512*2);
  u16* epb      = (u16*)alloc(64ULL*256*256*2);
  float* hTf    = (float*)alloc(16384ULL*4);
  float* cTf    = (float*)alloc(16384ULL*4);
  float* hTb    = (float*)alloc(16384ULL*4);
  float* cTb    = (float*)alloc(16384ULL*4);
  float* c0g    = (float*)alloc(16384ULL*4);
  float* c1g    = (float*)alloc(16384ULL*4);
  u16* h0buf    = (u16*)alloc(2ULL*16384*2);
  u16* h1buf    = (u16*)alloc(2ULL*16384*2);
  u16* ctxbuf   = (u16*)alloc(64ULL*512*2);
  u16* hG       = (u16*)alloc(4ULL*2*32*256*2);
  u16* dout     = (u16*)alloc(4096ULL*256*2);
  if (off > ws_size) return;

  hipMemsetAsync(dcnt, 0, 1024, stream);
  hipMemsetAsync(ecnt, 0, 1024, stream);

  prep_kernel<<<43008, 256, 0, stream>>>(encfWih, encfWhh, encbWih, encbWhh,
      d0Wih, d0Whh, d1Wih, d1Whh, attnW, projW,
      oWihf, oWhhf, oWihb, oWhhb, oW0, oW1, oWaH, oWaE, oprojW);

  gather_kernel<<<20480, 256, 0, stream>>>(src, tgt, src_emb, tgt_emb, xs, temb);

  gemm64<256,1><<<dim3(256,16), 256, 0, stream>>>(xs, 256, oWihf, 256, encfb, XWf, 1024);
  gemm64<256,1><<<dim3(256,16), 256, 0, stream>>>(xs, 256, oWihb, 256, encbb, XWb, 1024);

  encoder_kernel<<<16, 512, 0, stream>>>(XWf, XWb, oWhhf, oWhhb, enc, hTf, cTf, hTb, cTb, hG, ecnt);

  gemm64<512,1><<<dim3(256,4), 256, 0, stream>>>(enc, 512, oWaE, 512, attnb, epb, 256);

  init_states<<<64, 256, 0, stream>>>(hTf, hTb, cTf, cTb, c0g, c1g, h0buf, h1buf);

  decoder_kernel<<<64, 512, 0, stream>>>(epb, enc, temb, oWaH, oW0, oW1,
      attnv, d0b, d1b, c0g, c1g, h0buf, h1buf, ctxbuf, dout, dcnt);

  gemm64<256,0><<<dim3(64,500), 256, 0, stream>>>(dout, 256, oprojW, 256, projb, (float*)d_out, 32000);
}